// Round 11
// baseline (272.623 us; speedup 1.0000x reference)
//
#include <hip/hip_runtime.h>
#include <math.h>

#define BB 4
#define SS 8192
#define HH 16
#define DD 64
#define ROT 32
#define NG (BB * SS * HH)  // 524288 token-head rows
#define RPT 64             // rows per tile (4 tokens; wave = 1 token)
#define TILES 4            // tiles per block (even: unroll-2 rotation)
#define NBLK (NG / (RPT * TILES))  // 2048 blocks
#define TPB 256            // 4 waves
#define LSTR 65            // fallback kernel LDS stride

typedef float f32x4 __attribute__((ext_vector_type(4)));
typedef short bf16x8 __attribute__((ext_vector_type(8)));  // 8 bf16 = 4 VGPR

// ---------------------------------------------------------------------------
// Setup: G_comb (threads 0..63, column-op per row), then M = G @ matrix.
// Emits M split into bf16 hi/lo in PERMUTED MFMA B-fragment layout:
//   column groups G0 = even cols 0..30, G1 = odd cols 1..31,
//                 G2 = even cols 32..62, G3 = odd cols 33..63
//   (pair (2d,2d+1) of the RoPE epilogue lands e/o in the SAME lane).
//   Within a frag (B[k][vcol]): lane = ((k>>3)&3)*16 + v, elem j = k&7,
//   frag f = G*2 + (k>>5).  hi = truncate-to-bf16, lo = truncate(val-hi).
// i==j edge: .at chain leaves G[i,i]=sin -> column i scaled by sin.
// ---------------------------------------------------------------------------
__global__ void setup_GM(const float* __restrict__ thetas,
                         const float* __restrict__ tscale,
                         const int* __restrict__ pairs,
                         const float* __restrict__ matrix,
                         float* __restrict__ M,
                         unsigned short* __restrict__ Mhi,
                         unsigned short* __restrict__ Mlo) {
  __shared__ float Gs[DD][DD];
  const int t = threadIdx.x;
  if (t < DD) {
    for (int c = 0; c < DD; ++c) Gs[t][c] = (t == c) ? 1.0f : 0.0f;
    const float ts = tscale[0];
    for (int r = 0; r < ROT; ++r) {
      const int i = pairs[2 * r], j = pairs[2 * r + 1];
      const float th = thetas[r] * ts;
      const float cc = cosf(th), sn = sinf(th);
      if (i == j) {
        Gs[t][i] *= sn;
      } else {
        const float a = Gs[t][i], b = Gs[t][j];
        Gs[t][i] = a * cc + b * sn;
        Gs[t][j] = b * cc - a * sn;
      }
    }
  }
  __syncthreads();
  const int e = blockIdx.x * 256 + t;
  const int k = e >> 6, col = e & 63;  // k wave-uniform -> LDS broadcast
  float a0 = 0.f, a1 = 0.f, a2 = 0.f, a3 = 0.f;
  for (int kk = 0; kk < DD; kk += 4) {
    a0 = fmaf(Gs[k][kk], matrix[kk * DD + col], a0);
    a1 = fmaf(Gs[k][kk + 1], matrix[(kk + 1) * DD + col], a1);
    a2 = fmaf(Gs[k][kk + 2], matrix[(kk + 2) * DD + col], a2);
    a3 = fmaf(Gs[k][kk + 3], matrix[(kk + 3) * DD + col], a3);
  }
  const float val = (a0 + a1) + (a2 + a3);
  M[e] = val;

  const int G = ((col >> 5) << 1) | (col & 1);  // pair-parity column group
  const int v = (col >> 1) & 15;                // virtual col (pair index)
  const int lane = ((k >> 3) & 3) * 16 + v;
  const int f = G * 2 + (k >> 5);
  const int idx = (f * 64 + lane) * 8 + (k & 7);
  const unsigned int b = __float_as_uint(val);
  const unsigned int hb = b & 0xFFFF0000u;
  const float rem = val - __uint_as_float(hb);
  Mhi[idx] = (unsigned short)(b >> 16);
  Mlo[idx] = (unsigned short)(__float_as_uint(rem) >> 16);
}

// Per-pair cos/sin table PRESCALED by 32, packed per lane:
// tab2[s*64 + i*4 + {0,1,2,3}] = {32cos(s*invf[i]), 32sin(s*invf[i]),
//                                 32cos(s*invf[16+i]), 32sin(s*invf[16+i])}
__global__ void setup_tab2(const float* __restrict__ invf,
                           float* __restrict__ tab2) {
  const int idx = blockIdx.x * 256 + threadIdx.x;  // SS*16 f32x4 entries
  if (idx >= SS * 16) return;
  const int s = idx >> 4, i = idx & 15;
  const float a0 = (float)s * invf[i];
  const float a1 = (float)s * invf[16 + i];
  float4 v;
  v.x = 32.0f * cosf(a0);
  v.y = 32.0f * sinf(a0);
  v.z = 32.0f * cosf(a1);
  v.w = 32.0f * sinf(a1);
  ((float4*)tab2)[idx] = v;
}

// --- split-bf16 helpers (truncation: hi = top 16 bits; rem exact in f32) ---
__device__ __forceinline__ unsigned int pack_hi(float u, float v, float& ru,
                                                float& rv) {
  const unsigned int bu = __float_as_uint(u);
  const unsigned int bv = __float_as_uint(v);
  const unsigned int hv = bv & 0xFFFF0000u;
  ru = u - __uint_as_float(bu & 0xFFFF0000u);
  rv = v - __uint_as_float(hv);
  return (bu >> 16) | hv;
}
__device__ __forceinline__ unsigned int pack_lo(float ru, float rv) {
  return (__float_as_uint(ru) >> 16) | (__float_as_uint(rv) & 0xFFFF0000u);
}
__device__ __forceinline__ void cvt8(const f32x4 a, const f32x4 b, bf16x8& hi,
                                     bf16x8& lo) {
  unsigned int* hp = (unsigned int*)&hi;
  unsigned int* lp = (unsigned int*)&lo;
  float r0, r1;
  hp[0] = pack_hi(a[0], a[1], r0, r1);
  lp[0] = pack_lo(r0, r1);
  hp[1] = pack_hi(a[2], a[3], r0, r1);
  lp[1] = pack_lo(r0, r1);
  hp[2] = pack_hi(b[0], b[1], r0, r1);
  lp[2] = pack_lo(r0, r1);
  hp[3] = pack_hi(b[2], b[3], r0, r1);
  lp[3] = pack_lo(r0, r1);
}

// ---------------------------------------------------------------------------
// Main kernel (MFMA split-bf16, permuted-M, register-only):
//  - M resident in 64 VGPRs (8 hi + 8 lo permuted B-frags), loaded once.
//  - Depth-2 register prefetch (a/b rotation, unroll-2): load latency
//    covered by ~2 iterations of MFMA+epilogue (R10 was 1-deep: exposed).
//  - Permuted fragments put RoPE pair (e,o) in the SAME lane -> epilogue is
//    4 local FMAs per (g,q); NO shfl, NO LDS, NO barriers (R10's serial
//    chain: shfl(ds_swizzle) -> ds_write -> ds_read -> store, 3.1M bank
//    conflict cycles - all deleted).
//  - tab2: one f32x4 per tile, issued BEFORE the MFMAs (L2 latency hidden).
//  - Outputs NT-stored direct from regs in 64B-contiguous chunks
//    (16 lanes x consecutive cols per store instruction).
// ---------------------------------------------------------------------------
__global__ __launch_bounds__(TPB, 3) void apply_rot(
    const float* __restrict__ x, const unsigned short* __restrict__ Mhi,
    const unsigned short* __restrict__ Mlo, const float* __restrict__ tab2,
    float* __restrict__ out) {
  const int tid = threadIdx.x;
  const int w = tid >> 6;  // wave 0..3 = token within tile
  const int l = tid & 63;  // lane
  const int l15 = l & 15, lk = l >> 4;

  // M fragments: hi/lo. 16 coalesced dwordx4 loads, resident all-kernel.
  bf16x8 bh[8], bl[8];
#pragma unroll
  for (int f = 0; f < 8; ++f) {
    bh[f] = *(const bf16x8*)(Mhi + (f * 64 + l) * 8);
    bl[f] = *(const bf16x8*)(Mlo + (f * 64 + l) * 8);
  }

  const size_t R0 = (size_t)blockIdx.x * (RPT * TILES);
  const float* __restrict__ xp = x + (R0 + w * 16 + l15) * DD + lk * 8;
  float* __restrict__ ob = out + (R0 + w * 16) * DD;
  const int tok0 = (int)(R0 >> 4) + w;  // token index of tile 0 for this wave

  // Prologue: tiles 0 and 1 in flight (depth 2).
  f32x4 a0 = *(const f32x4*)(xp);
  f32x4 a1 = *(const f32x4*)(xp + 4);
  f32x4 a2 = *(const f32x4*)(xp + 32);
  f32x4 a3 = *(const f32x4*)(xp + 36);
  const float* __restrict__ xq = xp + (size_t)RPT * DD;
  f32x4 b0 = *(const f32x4*)(xq);
  f32x4 b1 = *(const f32x4*)(xq + 4);
  f32x4 b2 = *(const f32x4*)(xq + 32);
  f32x4 b3 = *(const f32x4*)(xq + 36);

#define PROC(C0, C1, C2, C3, T)                                              \
  {                                                                          \
    bf16x8 ah0, al0, ah1, al1;                                               \
    cvt8(C0, C1, ah0, al0);                                                  \
    cvt8(C2, C3, ah1, al1);                                                  \
    if ((T) + 2 < TILES) { /* refill this rotation slot: tile T+2 */         \
      const float* __restrict__ p = xp + (size_t)((T) + 2) * RPT * DD;       \
      C0 = *(const f32x4*)(p);                                               \
      C1 = *(const f32x4*)(p + 4);                                           \
      C2 = *(const f32x4*)(p + 32);                                          \
      C3 = *(const f32x4*)(p + 36);                                          \
    }                                                                        \
    const int spos = (tok0 + (T) * 4) & (SS - 1);                            \
    const f32x4 tv = *(const f32x4*)(tab2 + (size_t)spos * 64 + l15 * 4);    \
    f32x4 acc[4];                                                            \
    _Pragma("unroll") for (int G = 0; G < 4; ++G) {                          \
      f32x4 a_ = {0.f, 0.f, 0.f, 0.f};                                       \
      a_ = __builtin_amdgcn_mfma_f32_16x16x32_bf16(ah0, bh[2 * G], a_, 0, 0, \
                                                   0);                       \
      a_ = __builtin_amdgcn_mfma_f32_16x16x32_bf16(ah1, bh[2 * G + 1], a_,   \
                                                   0, 0, 0);                 \
      a_ = __builtin_amdgcn_mfma_f32_16x16x32_bf16(ah0, bl[2 * G], a_, 0, 0, \
                                                   0);                       \
      a_ = __builtin_amdgcn_mfma_f32_16x16x32_bf16(ah1, bl[2 * G + 1], a_,   \
                                                   0, 0, 0);                 \
      a_ = __builtin_amdgcn_mfma_f32_16x16x32_bf16(al0, bh[2 * G], a_, 0, 0, \
                                                   0);                       \
      a_ = __builtin_amdgcn_mfma_f32_16x16x32_bf16(al1, bh[2 * G + 1], a_,   \
                                                   0, 0, 0);                 \
      acc[G] = a_;                                                           \
    }                                                                        \
    float* __restrict__ og = ob + (size_t)(T)*RPT * DD;                      \
    _Pragma("unroll") for (int g = 0; g < 2; ++g) {                          \
      const f32x4 ae = acc[2 * g];     /* even cols = e of pair d */         \
      const f32x4 ao = acc[2 * g + 1]; /* odd cols  = o of pair d */         \
      const float cz = tv[2 * g], sz = tv[2 * g + 1];                        \
      float* __restrict__ ogg = og + g * 16 + l15;                           \
      _Pragma("unroll") for (int q = 0; q < 4; ++q) {                        \
        const float e_ = ae[q], o_ = ao[q];                                  \
        const float lo_ = fmaf(e_, cz, -(o_ * sz));                          \
        const float hi_ = fmaf(e_, sz, o_ * cz);                             \
        const int ro = (lk * 4 + q) * DD;                                    \
        __builtin_nontemporal_store(lo_, ogg + ro);                          \
        __builtin_nontemporal_store(hi_, ogg + ro + 32);                     \
      }                                                                      \
    }                                                                        \
  }

#pragma unroll 1
  for (int t = 0; t < TILES; t += 2) {
    PROC(a0, a1, a2, a3, t);
    PROC(b0, b1, b2, b3, t + 1);
  }
#undef PROC
}

// ---------------------------------------------------------------------------
// Fallback (no workspace table): R6's proven scalar kernel, invf path.
// ---------------------------------------------------------------------------
__global__ __launch_bounds__(256, 8) void apply_rot_fb(
    const float* __restrict__ x, const float* __restrict__ M,
    const float* __restrict__ invf, float* __restrict__ out) {
  __shared__ float lds[64 * LSTR];
  const int tid = threadIdx.x;
  const size_t R0 = (size_t)blockIdx.x * 64;
  const float4* __restrict__ xg = (const float4*)x + R0 * 16;
#pragma unroll
  for (int i = 0; i < 4; ++i) {
    const int f = i * 256 + tid;
    *(float4*)&lds[(f >> 4) * LSTR + (f & 15) * 4] = xg[f];
  }
  __syncthreads();
  const int r = tid & 63;
  const int h = __builtin_amdgcn_readfirstlane(tid >> 6);
  const float* __restrict__ Mh = M + h * 16;
  const float* __restrict__ xr = &lds[r * LSTR];
  float acc[16];
#pragma unroll
  for (int c = 0; c < 16; ++c) acc[c] = 0.0f;
#pragma unroll 4
  for (int k4 = 0; k4 < 16; ++k4) {
    const float4 xv = *(const float4*)&xr[k4 * 4];
    const float* __restrict__ m0 = Mh + k4 * 4 * DD;
#pragma unroll
    for (int c = 0; c < 16; ++c) acc[c] = fmaf(xv.x, m0[c], acc[c]);
#pragma unroll
    for (int c = 0; c < 16; ++c) acc[c] = fmaf(xv.y, m0[DD + c], acc[c]);
#pragma unroll
    for (int c = 0; c < 16; ++c) acc[c] = fmaf(xv.z, m0[2 * DD + c], acc[c]);
#pragma unroll
    for (int c = 0; c < 16; ++c) acc[c] = fmaf(xv.w, m0[3 * DD + c], acc[c]);
  }
  const int g = (int)R0 + r;
  const int spos = (g >> 4) & (SS - 1);
  float cz[8], sz[8];
#pragma unroll
  for (int d = 0; d < 8; ++d) {
    const float ang = (float)spos * invf[h * 8 + d];
    cz[d] = 32.0f * cosf(ang);
    sz[d] = 32.0f * sinf(ang);
  }
  float4 lov[2], hiv[2];
#pragma unroll
  for (int q = 0; q < 2; ++q) {
#pragma unroll
    for (int d = 0; d < 4; ++d) {
      const int dd = 4 * q + d;
      const float e = acc[2 * dd], o = acc[2 * dd + 1];
      ((float*)&lov[q])[d] = e * cz[dd] - o * sz[dd];
      ((float*)&hiv[q])[d] = e * sz[dd] + o * cz[dd];
    }
  }
  __syncthreads();
  float* __restrict__ orow = &lds[r * LSTR];
  *(float4*)&orow[8 * h + 0] = lov[0];
  *(float4*)&orow[8 * h + 4] = lov[1];
  *(float4*)&orow[32 + 8 * h + 0] = hiv[0];
  *(float4*)&orow[32 + 8 * h + 4] = hiv[1];
  __syncthreads();
  float4* __restrict__ og = (float4*)out + R0 * 16;
#pragma unroll
  for (int i = 0; i < 4; ++i) {
    const int f = i * 256 + tid;
    og[f] = *(float4*)&lds[(f >> 4) * LSTR + (f & 15) * 4];
  }
}

// ---------------------------------------------------------------------------
extern "C" void kernel_launch(void* const* d_in, const int* in_sizes, int n_in,
                              void* d_out, int out_size, void* d_ws,
                              size_t ws_size, hipStream_t stream) {
  const float* x = (const float*)d_in[0];       // (4, 8192, 1024) f32
  const float* matrix = (const float*)d_in[1];  // (64, 64) f32
  const float* thetas = (const float*)d_in[2];  // (32,) f32
  const float* tscale = (const float*)d_in[3];  // (1,) f32
  const float* invf = (const float*)d_in[4];    // (32,) f32
  const int* pairs = (const int*)d_in[5];       // (32, 2) i32
  float* out = (float*)d_out;

  // ws layout: M f32 (16KB) | Mhi u16 (8KB) | Mlo u16 (8KB) | tab2 f32 (2MB)
  float* M = (float*)d_ws;
  unsigned short* Mhi = (unsigned short*)(M + DD * DD);
  unsigned short* Mlo = Mhi + DD * DD;
  float* tab2 = (float*)(Mlo + DD * DD);
  const size_t need =
      (size_t)DD * DD * 4 + (size_t)DD * DD * 4 + (size_t)SS * 64 * 4;
  const bool have_tab = ws_size >= need;

  setup_GM<<<16, 256, 0, stream>>>(thetas, tscale, pairs, matrix, M, Mhi, Mlo);
  if (have_tab) {
    setup_tab2<<<(SS * 16) / 256, 256, 0, stream>>>(invf, tab2);
    apply_rot<<<NBLK, TPB, 0, stream>>>(x, Mhi, Mlo, tab2, out);
  } else {
    apply_rot_fb<<<NG / 64, 256, 0, stream>>>(x, M, invf, out);
  }
}

// Round 12
// 265.000 us; speedup vs baseline: 1.0288x; 1.0288x over previous
//
#include <hip/hip_runtime.h>
#include <math.h>

#define BB 4
#define SS 8192
#define HH 16
#define DD 64
#define ROT 32
#define NG (BB * SS * HH)  // 524288 token-head rows
#define RPT 64             // rows per tile (4 tokens; wave = 1 token)
#define TILES 4            // tiles per block (even: unroll-2 rotation)
#define NBLK (NG / (RPT * TILES))  // 2048 blocks
#define TPB 256            // 4 waves
#define LSTR 65            // fallback kernel LDS stride

typedef float f32x4 __attribute__((ext_vector_type(4)));
typedef float f32x2 __attribute__((ext_vector_type(2)));
typedef short bf16x8 __attribute__((ext_vector_type(8)));  // 8 bf16 = 4 VGPR

// ---------------------------------------------------------------------------
// Setup: G_comb (threads 0..63, column-op per row), then M = G @ matrix.
// Emits M split into bf16 hi/lo in PAIR-ADJACENT permuted B-frag layout:
//   fragment group G = col & 3, virtual col v = col >> 2.
//   So lane v holds: G0 = e(pair 2v), G1 = o(pair 2v), G2 = e(pair 2v+1),
//   G3 = o(pair 2v+1)  ->  RoPE pair is lane-local AND the lane's two lo
//   outputs (cols 2v, 2v+1) are ADJACENT: full-line dwordx2 NT stores.
//   Within a frag (B[k][v]): lane = ((k>>3)&3)*16 + v, elem j = k&7,
//   frag f = G*2 + (k>>5).  hi = truncate-to-bf16, lo = truncate(val-hi).
// i==j edge: .at chain leaves G[i,i]=sin -> column i scaled by sin.
// ---------------------------------------------------------------------------
__global__ void setup_GM(const float* __restrict__ thetas,
                         const float* __restrict__ tscale,
                         const int* __restrict__ pairs,
                         const float* __restrict__ matrix,
                         float* __restrict__ M,
                         unsigned short* __restrict__ Mhi,
                         unsigned short* __restrict__ Mlo) {
  __shared__ float Gs[DD][DD];
  const int t = threadIdx.x;
  if (t < DD) {
    for (int c = 0; c < DD; ++c) Gs[t][c] = (t == c) ? 1.0f : 0.0f;
    const float ts = tscale[0];
    for (int r = 0; r < ROT; ++r) {
      const int i = pairs[2 * r], j = pairs[2 * r + 1];
      const float th = thetas[r] * ts;
      const float cc = cosf(th), sn = sinf(th);
      if (i == j) {
        Gs[t][i] *= sn;
      } else {
        const float a = Gs[t][i], b = Gs[t][j];
        Gs[t][i] = a * cc + b * sn;
        Gs[t][j] = b * cc - a * sn;
      }
    }
  }
  __syncthreads();
  const int e = blockIdx.x * 256 + t;
  const int k = e >> 6, col = e & 63;  // k wave-uniform -> LDS broadcast
  float a0 = 0.f, a1 = 0.f, a2 = 0.f, a3 = 0.f;
  for (int kk = 0; kk < DD; kk += 4) {
    a0 = fmaf(Gs[k][kk], matrix[kk * DD + col], a0);
    a1 = fmaf(Gs[k][kk + 1], matrix[(kk + 1) * DD + col], a1);
    a2 = fmaf(Gs[k][kk + 2], matrix[(kk + 2) * DD + col], a2);
    a3 = fmaf(Gs[k][kk + 3], matrix[(kk + 3) * DD + col], a3);
  }
  const float val = (a0 + a1) + (a2 + a3);
  M[e] = val;

  const int G = col & 3;   // pair-adjacent column group
  const int v = col >> 2;  // virtual col
  const int lane = ((k >> 3) & 3) * 16 + v;
  const int f = G * 2 + (k >> 5);
  const int idx = (f * 64 + lane) * 8 + (k & 7);
  const unsigned int b = __float_as_uint(val);
  const unsigned int hb = b & 0xFFFF0000u;
  const float rem = val - __uint_as_float(hb);
  Mhi[idx] = (unsigned short)(b >> 16);
  Mlo[idx] = (unsigned short)(__float_as_uint(rem) >> 16);
}

// Per-lane cos/sin table PRESCALED by 32 for adjacent pairs:
// tab2[s*64 + v*4 + {0..3}] = {32cos(s*invf[2v]), 32sin(s*invf[2v]),
//                              32cos(s*invf[2v+1]), 32sin(s*invf[2v+1])}
__global__ void setup_tab2(const float* __restrict__ invf,
                           float* __restrict__ tab2) {
  const int idx = blockIdx.x * 256 + threadIdx.x;  // SS*16 f32x4 entries
  if (idx >= SS * 16) return;
  const int s = idx >> 4, v = idx & 15;
  const float a0 = (float)s * invf[2 * v];
  const float a1 = (float)s * invf[2 * v + 1];
  float4 t;
  t.x = 32.0f * cosf(a0);
  t.y = 32.0f * sinf(a0);
  t.z = 32.0f * cosf(a1);
  t.w = 32.0f * sinf(a1);
  ((float4*)tab2)[idx] = t;
}

// --- split-bf16 helpers (truncation: hi = top 16 bits; rem exact in f32) ---
__device__ __forceinline__ unsigned int pack_hi(float u, float v, float& ru,
                                                float& rv) {
  const unsigned int bu = __float_as_uint(u);
  const unsigned int bv = __float_as_uint(v);
  const unsigned int hv = bv & 0xFFFF0000u;
  ru = u - __uint_as_float(bu & 0xFFFF0000u);
  rv = v - __uint_as_float(hv);
  return (bu >> 16) | hv;
}
__device__ __forceinline__ unsigned int pack_lo(float ru, float rv) {
  return (__float_as_uint(ru) >> 16) | (__float_as_uint(rv) & 0xFFFF0000u);
}
__device__ __forceinline__ void cvt8(const f32x4 a, const f32x4 b, bf16x8& hi,
                                     bf16x8& lo) {
  unsigned int* hp = (unsigned int*)&hi;
  unsigned int* lp = (unsigned int*)&lo;
  float r0, r1;
  hp[0] = pack_hi(a[0], a[1], r0, r1);
  lp[0] = pack_lo(r0, r1);
  hp[1] = pack_hi(a[2], a[3], r0, r1);
  lp[1] = pack_lo(r0, r1);
  hp[2] = pack_hi(b[0], b[1], r0, r1);
  lp[2] = pack_lo(r0, r1);
  hp[3] = pack_hi(b[2], b[3], r0, r1);
  lp[3] = pack_lo(r0, r1);
}

// ---------------------------------------------------------------------------
// Main kernel (MFMA split-bf16, pair-adjacent permuted-M, register-only):
//  - M resident in 64 VGPRs (8 hi + 8 lo B-frags), loaded once per wave.
//  - Depth-2 register prefetch (a/b rotation, unroll-2).
//  - RoPE pair AND adjacency in the same lane -> epilogue is 8 local FMAs
//    per q-row; NO shfl, NO LDS, NO barriers, 0 bank conflicts.
//  - Stores: dwordx2 NT, 16 lanes x 8B = full 128B lines per instruction
//    (fixes R11's 64B-half-line write amplification: 171 MB -> 131 MB).
// ---------------------------------------------------------------------------
__global__ __launch_bounds__(TPB, 3) void apply_rot(
    const float* __restrict__ x, const unsigned short* __restrict__ Mhi,
    const unsigned short* __restrict__ Mlo, const float* __restrict__ tab2,
    float* __restrict__ out) {
  const int tid = threadIdx.x;
  const int w = tid >> 6;  // wave 0..3 = token within tile
  const int l = tid & 63;  // lane
  const int l15 = l & 15, lk = l >> 4;

  // M fragments: hi/lo. 16 coalesced dwordx4 loads, resident all-kernel.
  bf16x8 bh[8], bl[8];
#pragma unroll
  for (int f = 0; f < 8; ++f) {
    bh[f] = *(const bf16x8*)(Mhi + (f * 64 + l) * 8);
    bl[f] = *(const bf16x8*)(Mlo + (f * 64 + l) * 8);
  }

  const size_t R0 = (size_t)blockIdx.x * (RPT * TILES);
  const float* __restrict__ xp = x + (R0 + w * 16 + l15) * DD + lk * 8;
  float* __restrict__ ob = out + (R0 + w * 16) * DD;
  const int tok0 = (int)(R0 >> 4) + w;  // token index of tile 0 for this wave

  // Prologue: tiles 0 and 1 in flight (depth 2).
  f32x4 a0 = *(const f32x4*)(xp);
  f32x4 a1 = *(const f32x4*)(xp + 4);
  f32x4 a2 = *(const f32x4*)(xp + 32);
  f32x4 a3 = *(const f32x4*)(xp + 36);
  const float* __restrict__ xq = xp + (size_t)RPT * DD;
  f32x4 b0 = *(const f32x4*)(xq);
  f32x4 b1 = *(const f32x4*)(xq + 4);
  f32x4 b2 = *(const f32x4*)(xq + 32);
  f32x4 b3 = *(const f32x4*)(xq + 36);

#define PROC(C0, C1, C2, C3, T)                                               \
  {                                                                           \
    bf16x8 ah0, al0, ah1, al1;                                                \
    cvt8(C0, C1, ah0, al0);                                                   \
    cvt8(C2, C3, ah1, al1);                                                   \
    if ((T) + 2 < TILES) { /* refill this rotation slot: tile T+2 */          \
      const float* __restrict__ p = xp + (size_t)((T) + 2) * RPT * DD;        \
      C0 = *(const f32x4*)(p);                                                \
      C1 = *(const f32x4*)(p + 4);                                            \
      C2 = *(const f32x4*)(p + 32);                                           \
      C3 = *(const f32x4*)(p + 36);                                           \
    }                                                                         \
    const int spos = (tok0 + (T) * 4) & (SS - 1);                             \
    const f32x4 tv = *(const f32x4*)(tab2 + (size_t)spos * 64 + l15 * 4);     \
    f32x4 acc[4];                                                             \
    _Pragma("unroll") for (int G = 0; G < 4; ++G) {                           \
      f32x4 a_ = {0.f, 0.f, 0.f, 0.f};                                        \
      a_ = __builtin_amdgcn_mfma_f32_16x16x32_bf16(ah0, bh[2 * G], a_, 0, 0,  \
                                                   0);                        \
      a_ = __builtin_amdgcn_mfma_f32_16x16x32_bf16(ah1, bh[2 * G + 1], a_, 0, \
                                                   0, 0);                     \
      a_ = __builtin_amdgcn_mfma_f32_16x16x32_bf16(ah0, bl[2 * G], a_, 0, 0,  \
                                                   0);                        \
      a_ = __builtin_amdgcn_mfma_f32_16x16x32_bf16(ah1, bl[2 * G + 1], a_, 0, \
                                                   0, 0);                     \
      a_ = __builtin_amdgcn_mfma_f32_16x16x32_bf16(al0, bh[2 * G], a_, 0, 0,  \
                                                   0);                        \
      a_ = __builtin_amdgcn_mfma_f32_16x16x32_bf16(al1, bh[2 * G + 1], a_, 0, \
                                                   0, 0);                     \
      acc[G] = a_;                                                            \
    }                                                                         \
    float* __restrict__ og = ob + (size_t)(T)*RPT * DD;                       \
    const float cz0 = tv[0], sz0 = tv[1], cz1 = tv[2], sz1 = tv[3];           \
    _Pragma("unroll") for (int q = 0; q < 4; ++q) {                           \
      const float e0 = acc[0][q], o0 = acc[1][q];                             \
      const float e1 = acc[2][q], o1 = acc[3][q];                             \
      f32x2 lo, hi;                                                           \
      lo[0] = fmaf(e0, cz0, -(o0 * sz0));                                     \
      lo[1] = fmaf(e1, cz1, -(o1 * sz1));                                     \
      hi[0] = fmaf(e0, sz0, o0 * cz0);                                        \
      hi[1] = fmaf(e1, sz1, o1 * cz1);                                        \
      const int ro = (lk * 4 + q) * DD + 2 * l15;                             \
      __builtin_nontemporal_store(lo, (f32x2*)(og + ro));                     \
      __builtin_nontemporal_store(hi, (f32x2*)(og + ro + 32));                \
    }                                                                         \
  }

#pragma unroll 1
  for (int t = 0; t < TILES; t += 2) {
    PROC(a0, a1, a2, a3, t);
    PROC(b0, b1, b2, b3, t + 1);
  }
#undef PROC
}

// ---------------------------------------------------------------------------
// Fallback (no workspace table): R6's proven scalar kernel, invf path.
// ---------------------------------------------------------------------------
__global__ __launch_bounds__(256, 8) void apply_rot_fb(
    const float* __restrict__ x, const float* __restrict__ M,
    const float* __restrict__ invf, float* __restrict__ out) {
  __shared__ float lds[64 * LSTR];
  const int tid = threadIdx.x;
  const size_t R0 = (size_t)blockIdx.x * 64;
  const float4* __restrict__ xg = (const float4*)x + R0 * 16;
#pragma unroll
  for (int i = 0; i < 4; ++i) {
    const int f = i * 256 + tid;
    *(float4*)&lds[(f >> 4) * LSTR + (f & 15) * 4] = xg[f];
  }
  __syncthreads();
  const int r = tid & 63;
  const int h = __builtin_amdgcn_readfirstlane(tid >> 6);
  const float* __restrict__ Mh = M + h * 16;
  const float* __restrict__ xr = &lds[r * LSTR];
  float acc[16];
#pragma unroll
  for (int c = 0; c < 16; ++c) acc[c] = 0.0f;
#pragma unroll 4
  for (int k4 = 0; k4 < 16; ++k4) {
    const float4 xv = *(const float4*)&xr[k4 * 4];
    const float* __restrict__ m0 = Mh + k4 * 4 * DD;
#pragma unroll
    for (int c = 0; c < 16; ++c) acc[c] = fmaf(xv.x, m0[c], acc[c]);
#pragma unroll
    for (int c = 0; c < 16; ++c) acc[c] = fmaf(xv.y, m0[DD + c], acc[c]);
#pragma unroll
    for (int c = 0; c < 16; ++c) acc[c] = fmaf(xv.z, m0[2 * DD + c], acc[c]);
#pragma unroll
    for (int c = 0; c < 16; ++c) acc[c] = fmaf(xv.w, m0[3 * DD + c], acc[c]);
  }
  const int g = (int)R0 + r;
  const int spos = (g >> 4) & (SS - 1);
  float cz[8], sz[8];
#pragma unroll
  for (int d = 0; d < 8; ++d) {
    const float ang = (float)spos * invf[h * 8 + d];
    cz[d] = 32.0f * cosf(ang);
    sz[d] = 32.0f * sinf(ang);
  }
  float4 lov[2], hiv[2];
#pragma unroll
  for (int q = 0; q < 2; ++q) {
#pragma unroll
    for (int d = 0; d < 4; ++d) {
      const int dd = 4 * q + d;
      const float e = acc[2 * dd], o = acc[2 * dd + 1];
      ((float*)&lov[q])[d] = e * cz[dd] - o * sz[dd];
      ((float*)&hiv[q])[d] = e * sz[dd] + o * cz[dd];
    }
  }
  __syncthreads();
  float* __restrict__ orow = &lds[r * LSTR];
  *(float4*)&orow[8 * h + 0] = lov[0];
  *(float4*)&orow[8 * h + 4] = lov[1];
  *(float4*)&orow[32 + 8 * h + 0] = hiv[0];
  *(float4*)&orow[32 + 8 * h + 4] = hiv[1];
  __syncthreads();
  float4* __restrict__ og = (float4*)out + R0 * 16;
#pragma unroll
  for (int i = 0; i < 4; ++i) {
    const int f = i * 256 + tid;
    og[f] = *(float4*)&lds[(f >> 4) * LSTR + (f & 15) * 4];
  }
}

// ---------------------------------------------------------------------------
extern "C" void kernel_launch(void* const* d_in, const int* in_sizes, int n_in,
                              void* d_out, int out_size, void* d_ws,
                              size_t ws_size, hipStream_t stream) {
  const float* x = (const float*)d_in[0];       // (4, 8192, 1024) f32
  const float* matrix = (const float*)d_in[1];  // (64, 64) f32
  const float* thetas = (const float*)d_in[2];  // (32,) f32
  const float* tscale = (const float*)d_in[3];  // (1,) f32
  const float* invf = (const float*)d_in[4];    // (32,) f32
  const int* pairs = (const int*)d_in[5];       // (32, 2) i32
  float* out = (float*)d_out;

  // ws layout: M f32 (16KB) | Mhi u16 (8KB) | Mlo u16 (8KB) | tab2 f32 (2MB)
  float* M = (float*)d_ws;
  unsigned short* Mhi = (unsigned short*)(M + DD * DD);
  unsigned short* Mlo = Mhi + DD * DD;
  float* tab2 = (float*)(Mlo + DD * DD);
  const size_t need =
      (size_t)DD * DD * 4 + (size_t)DD * DD * 4 + (size_t)SS * 64 * 4;
  const bool have_tab = ws_size >= need;

  setup_GM<<<16, 256, 0, stream>>>(thetas, tscale, pairs, matrix, M, Mhi, Mlo);
  if (have_tab) {
    setup_tab2<<<(SS * 16) / 256, 256, 0, stream>>>(invf, tab2);
    apply_rot<<<NBLK, TPB, 0, stream>>>(x, Mhi, Mlo, tab2, out);
  } else {
    apply_rot_fb<<<NG / 64, 256, 0, stream>>>(x, M, invf, out);
  }
}

// Round 13
// 255.107 us; speedup vs baseline: 1.0687x; 1.0388x over previous
//
#include <hip/hip_runtime.h>
#include <math.h>

#define BB 4
#define SS 8192
#define HH 16
#define DD 64
#define ROT 32
#define NG (BB * SS * HH)  // 524288 token-head rows
#define TPB 256            // 4 waves; wave = 1 token per tile
#define TILES 2            // tokens per wave (both fully prefetched)
#define NBLK (NG / (16 * 4 * TILES))  // 4096 blocks
#define LSTR 65            // fallback kernel LDS stride

typedef float f32x4 __attribute__((ext_vector_type(4)));
typedef float f32x2 __attribute__((ext_vector_type(2)));
typedef short bf16x8 __attribute__((ext_vector_type(8)));  // 8 bf16 = 4 VGPR

// ---------------------------------------------------------------------------
// Setup: G_comb (threads 0..63, column-op per row), then M = G @ matrix.
// Emits M split into bf16 hi/lo in PAIR-ADJACENT permuted B-frag layout:
//   fragment group G = col & 3, virtual col v = col >> 2.
//   Lane v holds e/o of pairs 2v (G0/G1) and 2v+1 (G2/G3) -> RoPE is
//   lane-local and the two lo outputs (cols 2v,2v+1) are adjacent.
//   Within a frag (B[k][v]): lane = ((k>>3)&3)*16 + v, elem j = k&7,
//   frag f = G*2 + (k>>5).  hi = truncate-to-bf16, lo = truncate(val-hi).
// i==j edge: .at chain leaves G[i,i]=sin -> column i scaled by sin.
// ---------------------------------------------------------------------------
__global__ void setup_GM(const float* __restrict__ thetas,
                         const float* __restrict__ tscale,
                         const int* __restrict__ pairs,
                         const float* __restrict__ matrix,
                         float* __restrict__ M,
                         unsigned short* __restrict__ Mhi,
                         unsigned short* __restrict__ Mlo) {
  __shared__ float Gs[DD][DD];
  const int t = threadIdx.x;
  if (t < DD) {
    for (int c = 0; c < DD; ++c) Gs[t][c] = (t == c) ? 1.0f : 0.0f;
    const float ts = tscale[0];
    for (int r = 0; r < ROT; ++r) {
      const int i = pairs[2 * r], j = pairs[2 * r + 1];
      const float th = thetas[r] * ts;
      const float cc = cosf(th), sn = sinf(th);
      if (i == j) {
        Gs[t][i] *= sn;
      } else {
        const float a = Gs[t][i], b = Gs[t][j];
        Gs[t][i] = a * cc + b * sn;
        Gs[t][j] = b * cc - a * sn;
      }
    }
  }
  __syncthreads();
  const int e = blockIdx.x * 256 + t;
  const int k = e >> 6, col = e & 63;  // k wave-uniform -> LDS broadcast
  float a0 = 0.f, a1 = 0.f, a2 = 0.f, a3 = 0.f;
  for (int kk = 0; kk < DD; kk += 4) {
    a0 = fmaf(Gs[k][kk], matrix[kk * DD + col], a0);
    a1 = fmaf(Gs[k][kk + 1], matrix[(kk + 1) * DD + col], a1);
    a2 = fmaf(Gs[k][kk + 2], matrix[(kk + 2) * DD + col], a2);
    a3 = fmaf(Gs[k][kk + 3], matrix[(kk + 3) * DD + col], a3);
  }
  const float val = (a0 + a1) + (a2 + a3);
  M[e] = val;

  const int G = col & 3;   // pair-adjacent column group
  const int v = col >> 2;  // virtual col
  const int lane = ((k >> 3) & 3) * 16 + v;
  const int f = G * 2 + (k >> 5);
  const int idx = (f * 64 + lane) * 8 + (k & 7);
  const unsigned int b = __float_as_uint(val);
  const unsigned int hb = b & 0xFFFF0000u;
  const float rem = val - __uint_as_float(hb);
  Mhi[idx] = (unsigned short)(b >> 16);
  Mlo[idx] = (unsigned short)(__float_as_uint(rem) >> 16);
}

// Per-lane cos/sin table PRESCALED by 32 for adjacent pairs:
// tab2[s*64 + v*4 + {0..3}] = {32cos(s*invf[2v]), 32sin(s*invf[2v]),
//                              32cos(s*invf[2v+1]), 32sin(s*invf[2v+1])}
__global__ void setup_tab2(const float* __restrict__ invf,
                           float* __restrict__ tab2) {
  const int idx = blockIdx.x * 256 + threadIdx.x;  // SS*16 f32x4 entries
  if (idx >= SS * 16) return;
  const int s = idx >> 4, v = idx & 15;
  const float a0 = (float)s * invf[2 * v];
  const float a1 = (float)s * invf[2 * v + 1];
  float4 t;
  t.x = 32.0f * cosf(a0);
  t.y = 32.0f * sinf(a0);
  t.z = 32.0f * cosf(a1);
  t.w = 32.0f * sinf(a1);
  ((float4*)tab2)[idx] = t;
}

// --- split-bf16 helpers (truncation: hi = top 16 bits; rem exact in f32) ---
__device__ __forceinline__ unsigned int pack_hi(float u, float v, float& ru,
                                                float& rv) {
  const unsigned int bu = __float_as_uint(u);
  const unsigned int bv = __float_as_uint(v);
  const unsigned int hv = bv & 0xFFFF0000u;
  ru = u - __uint_as_float(bu & 0xFFFF0000u);
  rv = v - __uint_as_float(hv);
  return (bu >> 16) | hv;
}
__device__ __forceinline__ unsigned int pack_lo(float ru, float rv) {
  return (__float_as_uint(ru) >> 16) | (__float_as_uint(rv) & 0xFFFF0000u);
}
__device__ __forceinline__ void cvt8(const f32x4 a, const f32x4 b, bf16x8& hi,
                                     bf16x8& lo) {
  unsigned int* hp = (unsigned int*)&hi;
  unsigned int* lp = (unsigned int*)&lo;
  float r0, r1;
  hp[0] = pack_hi(a[0], a[1], r0, r1);
  lp[0] = pack_lo(r0, r1);
  hp[1] = pack_hi(a[2], a[3], r0, r1);
  lp[1] = pack_lo(r0, r1);
  hp[2] = pack_hi(b[0], b[1], r0, r1);
  lp[2] = pack_lo(r0, r1);
  hp[3] = pack_hi(b[2], b[3], r0, r1);
  lp[3] = pack_lo(r0, r1);
}

// One token's worth of compute: cvt -> 24 MFMA -> RoPE -> 8 coalesced
// dwordx2 stores (REGULAR cached stores this round: the NT-vs-cached A/B).
__device__ __forceinline__ void proc_token(
    const f32x4 c0, const f32x4 c1, const f32x4 c2, const f32x4 c3,
    const f32x4 tv, const bf16x8* bh, const bf16x8* bl,
    float* __restrict__ og, const int lk, const int l15) {
  bf16x8 ah0, al0, ah1, al1;
  cvt8(c0, c1, ah0, al0);
  cvt8(c2, c3, ah1, al1);
  f32x4 acc[4];
#pragma unroll
  for (int G = 0; G < 4; ++G) {
    f32x4 a_ = {0.f, 0.f, 0.f, 0.f};
    a_ = __builtin_amdgcn_mfma_f32_16x16x32_bf16(ah0, bh[2 * G], a_, 0, 0, 0);
    a_ = __builtin_amdgcn_mfma_f32_16x16x32_bf16(ah1, bh[2 * G + 1], a_, 0, 0, 0);
    a_ = __builtin_amdgcn_mfma_f32_16x16x32_bf16(ah0, bl[2 * G], a_, 0, 0, 0);
    a_ = __builtin_amdgcn_mfma_f32_16x16x32_bf16(ah1, bl[2 * G + 1], a_, 0, 0, 0);
    a_ = __builtin_amdgcn_mfma_f32_16x16x32_bf16(al0, bh[2 * G], a_, 0, 0, 0);
    a_ = __builtin_amdgcn_mfma_f32_16x16x32_bf16(al1, bh[2 * G + 1], a_, 0, 0, 0);
    acc[G] = a_;
  }
  const float cz0 = tv[0], sz0 = tv[1], cz1 = tv[2], sz1 = tv[3];
#pragma unroll
  for (int q = 0; q < 4; ++q) {
    const float e0 = acc[0][q], o0 = acc[1][q];
    const float e1 = acc[2][q], o1 = acc[3][q];
    f32x2 lo, hi;
    lo[0] = fmaf(e0, cz0, -(o0 * sz0));
    lo[1] = fmaf(e1, cz1, -(o1 * sz1));
    hi[0] = fmaf(e0, sz0, o0 * cz0);
    hi[1] = fmaf(e1, sz1, o1 * cz1);
    const int ro = (lk * 4 + q) * DD + 2 * l15;
    *(f32x2*)(og + ro) = lo;        // regular store: L2 write-combining
    *(f32x2*)(og + ro + 32) = hi;   // (full 128B lines per instruction)
  }
}

// ---------------------------------------------------------------------------
// Main kernel (MFMA split-bf16, pair-adjacent permuted-M, register-only).
// R13 A/B: REGULAR stores instead of NT. Rationale: every NT round capped at
// ~2.45-2.6 TB/s effective HBM; the 6.29 TB/s copy ceiling (m13) used cached
// stores (L2 absorbs write bursts, avoids fine-grain read/write turnaround
// at DRAM). Structure: wave = 1 token; 2 tokens/wave both fully prefetched
// in the prologue; issue order a-loads, tv0, b-loads, tv1 so tile0's
// epilogue vmcnt never drains tile1's stream. No LDS, no barriers, no shfl.
// ---------------------------------------------------------------------------
__global__ __launch_bounds__(TPB, 3) void apply_rot(
    const float* __restrict__ x, const unsigned short* __restrict__ Mhi,
    const unsigned short* __restrict__ Mlo, const float* __restrict__ tab2,
    float* __restrict__ out) {
  const int tid = threadIdx.x;
  const int w = tid >> 6;  // wave 0..3
  const int l = tid & 63;  // lane
  const int l15 = l & 15, lk = l >> 4;

  // M fragments: hi/lo. 16 coalesced dwordx4 loads, resident all-kernel.
  bf16x8 bh[8], bl[8];
#pragma unroll
  for (int f = 0; f < 8; ++f) {
    bh[f] = *(const bf16x8*)(Mhi + (f * 64 + l) * 8);
    bl[f] = *(const bf16x8*)(Mlo + (f * 64 + l) * 8);
  }

  const size_t tok0 = (size_t)blockIdx.x * 8 + w;  // wave's token, tile 0
  const size_t tok1 = tok0 + 4;                    // tile 1
  const float* __restrict__ xp0 = x + (tok0 * 16 + l15) * DD + lk * 8;
  const float* __restrict__ xp1 = x + (tok1 * 16 + l15) * DD + lk * 8;

  // Prologue: everything in flight. Order: a, tv0, b, tv1.
  const f32x4 a0 = *(const f32x4*)(xp0);
  const f32x4 a1 = *(const f32x4*)(xp0 + 4);
  const f32x4 a2 = *(const f32x4*)(xp0 + 32);
  const f32x4 a3 = *(const f32x4*)(xp0 + 36);
  const int sp0 = (int)(tok0 & (SS - 1));
  const f32x4 tv0 = *(const f32x4*)(tab2 + (size_t)sp0 * 64 + l15 * 4);
  const f32x4 b0 = *(const f32x4*)(xp1);
  const f32x4 b1 = *(const f32x4*)(xp1 + 4);
  const f32x4 b2 = *(const f32x4*)(xp1 + 32);
  const f32x4 b3 = *(const f32x4*)(xp1 + 36);
  const int sp1 = (int)(tok1 & (SS - 1));
  const f32x4 tv1 = *(const f32x4*)(tab2 + (size_t)sp1 * 64 + l15 * 4);

  proc_token(a0, a1, a2, a3, tv0, bh, bl, out + tok0 * 16 * DD, lk, l15);
  proc_token(b0, b1, b2, b3, tv1, bh, bl, out + tok1 * 16 * DD, lk, l15);
}

// ---------------------------------------------------------------------------
// Fallback (no workspace table): R6's proven scalar kernel, invf path.
// ---------------------------------------------------------------------------
__global__ __launch_bounds__(256, 8) void apply_rot_fb(
    const float* __restrict__ x, const float* __restrict__ M,
    const float* __restrict__ invf, float* __restrict__ out) {
  __shared__ float lds[64 * LSTR];
  const int tid = threadIdx.x;
  const size_t R0 = (size_t)blockIdx.x * 64;
  const float4* __restrict__ xg = (const float4*)x + R0 * 16;
#pragma unroll
  for (int i = 0; i < 4; ++i) {
    const int f = i * 256 + tid;
    *(float4*)&lds[(f >> 4) * LSTR + (f & 15) * 4] = xg[f];
  }
  __syncthreads();
  const int r = tid & 63;
  const int h = __builtin_amdgcn_readfirstlane(tid >> 6);
  const float* __restrict__ Mh = M + h * 16;
  const float* __restrict__ xr = &lds[r * LSTR];
  float acc[16];
#pragma unroll
  for (int c = 0; c < 16; ++c) acc[c] = 0.0f;
#pragma unroll 4
  for (int k4 = 0; k4 < 16; ++k4) {
    const float4 xv = *(const float4*)&xr[k4 * 4];
    const float* __restrict__ m0 = Mh + k4 * 4 * DD;
#pragma unroll
    for (int c = 0; c < 16; ++c) acc[c] = fmaf(xv.x, m0[c], acc[c]);
#pragma unroll
    for (int c = 0; c < 16; ++c) acc[c] = fmaf(xv.y, m0[DD + c], acc[c]);
#pragma unroll
    for (int c = 0; c < 16; ++c) acc[c] = fmaf(xv.z, m0[2 * DD + c], acc[c]);
#pragma unroll
    for (int c = 0; c < 16; ++c) acc[c] = fmaf(xv.w, m0[3 * DD + c], acc[c]);
  }
  const int g = (int)R0 + r;
  const int spos = (g >> 4) & (SS - 1);
  float cz[8], sz[8];
#pragma unroll
  for (int d = 0; d < 8; ++d) {
    const float ang = (float)spos * invf[h * 8 + d];
    cz[d] = 32.0f * cosf(ang);
    sz[d] = 32.0f * sinf(ang);
  }
  float4 lov[2], hiv[2];
#pragma unroll
  for (int q = 0; q < 2; ++q) {
#pragma unroll
    for (int d = 0; d < 4; ++d) {
      const int dd = 4 * q + d;
      const float e = acc[2 * dd], o = acc[2 * dd + 1];
      ((float*)&lov[q])[d] = e * cz[dd] - o * sz[dd];
      ((float*)&hiv[q])[d] = e * sz[dd] + o * cz[dd];
    }
  }
  __syncthreads();
  float* __restrict__ orow = &lds[r * LSTR];
  *(float4*)&orow[8 * h + 0] = lov[0];
  *(float4*)&orow[8 * h + 4] = lov[1];
  *(float4*)&orow[32 + 8 * h + 0] = hiv[0];
  *(float4*)&orow[32 + 8 * h + 4] = hiv[1];
  __syncthreads();
  float4* __restrict__ og = (float4*)out + R0 * 16;
#pragma unroll
  for (int i = 0; i < 4; ++i) {
    const int f = i * 256 + tid;
    og[f] = *(float4*)&lds[(f >> 4) * LSTR + (f & 15) * 4];
  }
}

// ---------------------------------------------------------------------------
extern "C" void kernel_launch(void* const* d_in, const int* in_sizes, int n_in,
                              void* d_out, int out_size, void* d_ws,
                              size_t ws_size, hipStream_t stream) {
  const float* x = (const float*)d_in[0];       // (4, 8192, 1024) f32
  const float* matrix = (const float*)d_in[1];  // (64, 64) f32
  const float* thetas = (const float*)d_in[2];  // (32,) f32
  const float* tscale = (const float*)d_in[3];  // (1,) f32
  const float* invf = (const float*)d_in[4];    // (32,) f32
  const int* pairs = (const int*)d_in[5];       // (32, 2) i32
  float* out = (float*)d_out;

  // ws layout: M f32 (16KB) | Mhi u16 (8KB) | Mlo u16 (8KB) | tab2 f32 (2MB)
  float* M = (float*)d_ws;
  unsigned short* Mhi = (unsigned short*)(M + DD * DD);
  unsigned short* Mlo = Mhi + DD * DD;
  float* tab2 = (float*)(Mlo + DD * DD);
  const size_t need =
      (size_t)DD * DD * 4 + (size_t)DD * DD * 4 + (size_t)SS * 64 * 4;
  const bool have_tab = ws_size >= need;

  setup_GM<<<16, 256, 0, stream>>>(thetas, tscale, pairs, matrix, M, Mhi, Mlo);
  if (have_tab) {
    setup_tab2<<<(SS * 16) / 256, 256, 0, stream>>>(invf, tab2);
    apply_rot<<<NBLK, TPB, 0, stream>>>(x, Mhi, Mlo, tab2, out);
  } else {
    apply_rot_fb<<<NG / 64, 256, 0, stream>>>(x, M, invf, out);
  }
}